// Round 7
// baseline (279.703 us; speedup 1.0000x reference)
//
#include <hip/hip_runtime.h>
#include <hip/hip_bf16.h>

// Problem: B=4, L=2048, C=1024, H=16, D=64, M=B*L=8192. I/O f32.
// Internal: bf16 MFMA, f32 accumulate. Verified absmax 9.8e-4 (thr 4.04e-3).
// R16: three coordinated changes (GEMM structure + k-norm fusion):
//   (a) GEMM 2-phase prefetch: old loop was barrier/gload_lds/barrier/
//       compute — the 2nd __syncthreads (= s_waitcnt vmcnt(0)+s_barrier)
//       drained the loads RIGHT AFTER issue: full ~250cy latency exposed
//       every K-step. New: double-buffered LDS, prefetch next tile at
//       loop-top, ONE barrier/iter — loads fly under ~400cy of compute
//       (the R12-attn-proven issue-early/drain-late skeleton). R15's
//       slot-XOR bank swizzle kept on both sides.
//   (b) k L2-norm fused into QKV GEMM epilogue (KNORM blocks bn in
//       [1024,2048)): each wave's wc-span = exactly one head's 64 cols;
//       per-row sumsq = 5 shfl_xor (halves are distinct rows; masks<=16
//       keep them separate). Normalized k written to the qkv k-plane.
//   (c) kb buffer deleted; attn reads K from the qkv k-plane (each 128B
//       line = one (l,h) k-row — same L2 footprint); prep_kv -> prep_v
//       (v transpose only). Saves ~33MB traffic + half of prep_kv.

typedef __attribute__((ext_vector_type(8))) short bf16x8;
typedef __attribute__((ext_vector_type(16))) float f32x16;

#define MAXLOG 4.60517018598809f   // ln(100)
#define LOG2E  1.4426950408889634f

__device__ __forceinline__ float bf2f(unsigned short u) {
    union { unsigned int i; float f; } v; v.i = ((unsigned int)u) << 16; return v.f;
}
__device__ __forceinline__ unsigned short f2bf(float f) {
    union { float f; unsigned int i; } v; v.f = f;
    unsigned int x = v.i;
    return (unsigned short)((x + 0x7FFFu + ((x >> 16) & 1u)) >> 16);  // RNE
}
__device__ __forceinline__ unsigned fbits(float f) {
    union { float f; unsigned u; } v; v.f = f; return v.u;
}
__device__ __forceinline__ bf16x8 pack8(const float* __restrict__ p) {
    float4 a = *(const float4*)p;
    float4 b = *(const float4*)(p + 4);
    bf16x8 r;
    r[0] = (short)f2bf(a.x); r[1] = (short)f2bf(a.y);
    r[2] = (short)f2bf(a.z); r[3] = (short)f2bf(a.w);
    r[4] = (short)f2bf(b.x); r[5] = (short)f2bf(b.y);
    r[6] = (short)f2bf(b.z); r[7] = (short)f2bf(b.w);
    return r;
}
__device__ __forceinline__ void gload_lds16(const void* g, void* l) {
    __builtin_amdgcn_global_load_lds((const __attribute__((address_space(1))) void*)g,
                                     (__attribute__((address_space(3))) void*)l, 16, 0, 0);
}

// ---------------------------------------- fused prep: casts + bias (1 kernel)
__global__ __launch_bounds__(256) void k_prep(
    const float* __restrict__ x, const float* __restrict__ Wqkv,
    const float* __restrict__ Wp, const float* __restrict__ qbia,
    const float* __restrict__ vbia,
    unsigned short* __restrict__ xb, unsigned short* __restrict__ Wqkvb,
    unsigned short* __restrict__ Wpb, float* __restrict__ bias3)
{
    int i = blockIdx.x * 256 + threadIdx.x;
    if (i < 1048576) {
        *(bf16x8*)&xb[(long)i * 8] = pack8(&x[(long)i * 8]);
    } else if (i < 1441792) {
        int j = i - 1048576;
        *(bf16x8*)&Wqkvb[(long)j * 8] = pack8(&Wqkv[(long)j * 8]);
    } else if (i < 1572864) {
        int j = i - 1441792;
        *(bf16x8*)&Wpb[(long)j * 8] = pack8(&Wp[(long)j * 8]);
    } else if (i < 1573248) {
        int j = (i - 1572864) * 8;
        for (int u = 0; u < 8; ++u) {
            int n = j + u;
            float v = 0.0f;
            if (n < 1024) v = qbia[n];
            else if (n >= 2048) v = vbia[n - 2048];
            bias3[n] = v;
        }
    }
}

// ------------------------- GEMM, B^T input, 32x32x16 MFMA, global_load_lds
// R16: double-buffered LDS + loop-top prefetch, one barrier/iter.
// R15 slot-XOR swizzle on both staging source and fragment read.
// KNORM: blocks covering cols [1024,2048) L2-normalize rows per head.
template<bool OUT_F32, bool KNORM>
__global__ __launch_bounds__(256) void k_gemm_lds(
    const unsigned short* __restrict__ A, const unsigned short* __restrict__ Bh,
    const float* __restrict__ bias, void* __restrict__ Cp, int N, int K)
{
    __shared__ unsigned short As[2][128 * 32];
    __shared__ unsigned short Bs[2][128 * 32];
    const int t = threadIdx.x, wave = t >> 6, lane = t & 63;
    const int m32 = lane & 31, half = lane >> 5;
    const int bm = blockIdx.x * 128, bn = blockIdx.y * 128;
    const int wr = (wave >> 1) * 64, wc = (wave & 1) * 64;
    f32x16 acc[2][2] = {};

    const int srow = lane >> 2;        // 0..15
    // write-side swizzle: slot = (lane&3) ^ ((srow>>1)&3)
    const int scol = (((lane & 3) ^ ((lane >> 3) & 3))) * 8;
    const int c0 = wave * 2, c1 = wave * 2 + 1;
    const long ga0 = (long)(bm + c0 * 16 + srow) * K + scol;
    const long ga1 = (long)(bm + c1 * 16 + srow) * K + scol;
    const long gb0 = (long)(bn + c0 * 16 + srow) * K + scol;
    const long gb1 = (long)(bn + c1 * 16 + srow) * K + scol;

    // read-side swizzle term for this lane's fragment rows
    const int swz = (m32 >> 1) & 3;

    // prologue: stage tile 0 into buffer 0
    gload_lds16(&A[ga0], &As[0][c0 * 512]);
    gload_lds16(&A[ga1], &As[0][c1 * 512]);
    gload_lds16(&Bh[gb0], &Bs[0][c0 * 512]);
    gload_lds16(&Bh[gb1], &Bs[0][c1 * 512]);
    __syncthreads();

    int cur = 0;
    for (int kt = 0; kt < K; kt += 32) {
        const int nxt = kt + 32;
        if (nxt < K) {   // issue next-tile loads EARLY; they fly under compute
            gload_lds16(&A[ga0 + nxt], &As[cur ^ 1][c0 * 512]);
            gload_lds16(&A[ga1 + nxt], &As[cur ^ 1][c1 * 512]);
            gload_lds16(&Bh[gb0 + nxt], &Bs[cur ^ 1][c0 * 512]);
            gload_lds16(&Bh[gb1 + nxt], &Bs[cur ^ 1][c1 * 512]);
        }
        bf16x8 af[2][2], bfr[2][2];
        for (int mt = 0; mt < 2; ++mt)
            for (int f = 0; f < 2; ++f)
                af[mt][f] = *(const bf16x8*)&As[cur][(wr + mt * 32 + m32) * 32 +
                                                    (((f * 2 + half) ^ swz) * 8)];
        for (int nt = 0; nt < 2; ++nt)
            for (int f = 0; f < 2; ++f)
                bfr[nt][f] = *(const bf16x8*)&Bs[cur][(wc + nt * 32 + m32) * 32 +
                                                     (((f * 2 + half) ^ swz) * 8)];
        for (int f = 0; f < 2; ++f)
            for (int mt = 0; mt < 2; ++mt)
                for (int nt = 0; nt < 2; ++nt)
                    acc[mt][nt] = __builtin_amdgcn_mfma_f32_32x32x16_bf16(
                        af[mt][f], bfr[nt][f], acc[mt][nt], 0, 0, 0);
        // one barrier: (a) drains this iter's prefetch (vmcnt0), (b) all
        // reads of buf[cur] done -> safe to restage it next iter.
        __syncthreads();
        cur ^= 1;
    }

    // epilogue: 32x32 C/D layout col=lane&31, row=(r&3)+8*(r>>2)+4*half.
    // KNORM blocks: wave's wc-span = one head's 64 cols; halves hold
    // DIFFERENT rows -> shfl_xor masks <=16 reduce each half separately.
    const bool isk = KNORM && (bn >= 1024) && (bn < 2048);
    const float bv0 = bias[bn + wc + m32];
    const float bv1 = bias[bn + wc + 32 + m32];
    for (int mt = 0; mt < 2; ++mt)
        for (int r = 0; r < 16; ++r) {
            int gm = bm + wr + mt * 32 + (r & 3) + 8 * (r >> 2) + 4 * half;
            float inv = 1.0f;
            if (isk) {
                float ss = acc[mt][0][r] * acc[mt][0][r]
                         + acc[mt][1][r] * acc[mt][1][r];
                ss += __shfl_xor(ss, 1, 64);
                ss += __shfl_xor(ss, 2, 64);
                ss += __shfl_xor(ss, 4, 64);
                ss += __shfl_xor(ss, 8, 64);
                ss += __shfl_xor(ss, 16, 64);
                inv = 1.0f / fmaxf(sqrtf(ss), 1e-12f);
            }
            for (int nt = 0; nt < 2; ++nt) {
                int gn = bn + wc + nt * 32 + m32;
                float val = acc[mt][nt][r] + (nt ? bv1 : bv0);
                if (isk) val *= inv;
                if (OUT_F32) ((float*)Cp)[(long)gm * N + gn] = val;
                else ((unsigned short*)Cp)[(long)gm * N + gn] = f2bf(val);
            }
        }
}

// ------------------------- v transpose (k-norm now fused into QKV GEMM)
__global__ __launch_bounds__(256) void k_prep_v(
    const unsigned short* __restrict__ qkv, unsigned short* __restrict__ vT)
{
    __shared__ unsigned short Vsh[64 * 72];
    const int t = threadIdx.x;
    const int bh = blockIdx.y, l0 = blockIdx.x * 64;
    const int h = bh & 15, b = bh >> 4;
    const int ll = t >> 2, c16 = (t & 3) * 16;
    const long rowbase = (long)(b * 2048 + l0 + ll) * 3072;

    *(bf16x8*)&Vsh[ll * 72 + c16]     = *(const bf16x8*)&qkv[rowbase + 2048 + h * 64 + c16];
    *(bf16x8*)&Vsh[ll * 72 + c16 + 8] = *(const bf16x8*)&qkv[rowbase + 2048 + h * 64 + c16 + 8];
    __syncthreads();
    const int d = t >> 2, ls = (t & 3) * 16;
    unsigned short tmp[16];
    for (int j = 0; j < 16; ++j) tmp[j] = Vsh[(ls + j) * 72 + d];
    long dst = (long)(bh * 64 + d) * 2048 + l0 + ls;
    *(bf16x8*)&vT[dst]     = *(bf16x8*)&tmp[0];
    *(bf16x8*)&vT[dst + 8] = *(bf16x8*)&tmp[8];
}

// ------------------------------------------------------------ flash attention
// 32x32x16 MFMA, S^T form (key-permutation: P stays in registers).
// R14 structure (64 q-rows/wave, two 32-q groups sharing K/V frag regs).
// R16: K staged from the qkv k-plane (normalized in the GEMM epilogue);
// kb buffer removed. Rowsum in lacc MFMAs.
__global__ __launch_bounds__(256, 2) void k_attn32(
    const unsigned short* __restrict__ qkv,
    const unsigned short* __restrict__ vT, const float* __restrict__ sml,
    unsigned short* __restrict__ attn)
{
    __shared__ unsigned short Ks[2][64 * 72];
    __shared__ unsigned short Vs[2][64 * 72];
    const int t = threadIdx.x, wave = t >> 6, lane = t & 63;
    const int m32 = lane & 31, half = lane >> 5;
    // XCD-chunked swizzle: 512 blocks, 64 logical per XCD = 8 (b,h) groups
    // (~4MB K/V = L2 size). Proven lever (R10: FETCH 139MB -> 24.6MB).
    const int wg = blockIdx.x;
    const int logical = (wg & 7) * 64 + (wg >> 3);
    const int bh = logical >> 3, qblk = logical & 7;
    const int h = bh & 15, b = bh >> 4;
    const int q0 = qblk * 256 + wave * 64;     // rows q0..q0+31 (A), q0+32..q0+63 (B)
    const float scale = __expf(fminf(sml[h], MAXLOG));
    const float c2 = scale * LOG2E;   // shift for the (rare) large-scale path

    // permuted physical key row for the S^T A-frag (swap quads 1<->2, 5<->6)
    const int qd = m32 >> 2, lo = qd & 3;
    const int prow = ((((lo == 1) || (lo == 2)) ? (qd ^ 3) : qd) << 2) | (m32 & 3);

    // fused q load + L2-normalize for both q-groups; scale folded with LOG2E
    bf16x8 aqA[4], aqB[4];
    {
        long base = (long)(b * 2048 + q0 + m32) * 3072 + h * 64;
        float e[32]; float ss = 0.f;
        for (int f = 0; f < 4; ++f) {
            aqA[f] = *(const bf16x8*)&qkv[base + f * 16 + half * 8];
            for (int j = 0; j < 8; ++j) { float x = bf2f((unsigned short)aqA[f][j]); e[f * 8 + j] = x; ss += x * x; }
        }
        ss += __shfl_xor(ss, 32, 64);
        float rs = (scale * LOG2E) / fmaxf(sqrtf(ss), 1e-12f);
        for (int f = 0; f < 4; ++f)
            for (int j = 0; j < 8; ++j) aqA[f][j] = (short)f2bf(e[f * 8 + j] * rs);
    }
    {
        long base = (long)(b * 2048 + q0 + 32 + m32) * 3072 + h * 64;
        float e[32]; float ss = 0.f;
        for (int f = 0; f < 4; ++f) {
            aqB[f] = *(const bf16x8*)&qkv[base + f * 16 + half * 8];
            for (int j = 0; j < 8; ++j) { float x = bf2f((unsigned short)aqB[f][j]); e[f * 8 + j] = x; ss += x * x; }
        }
        ss += __shfl_xor(ss, 32, 64);
        float rs = (scale * LOG2E) / fmaxf(sqrtf(ss), 1e-12f);
        for (int f = 0; f < 4; ++f)
            for (int j = 0; j < 8; ++j) aqB[f][j] = (short)f2bf(e[f * 8 + j] * rs);
    }

    f32x16 oA0 = {}, oA1 = {}, lA = {};
    f32x16 oB0 = {}, oB1 = {}, lB = {};
    bf16x8 ones; for (int i = 0; i < 8; ++i) ones[i] = (short)0x3F80;
    const int sr = t >> 2, sc = (t & 3) * 16;
    // K rows live in the qkv k-plane: row l at qkv[(b*2048+l)*3072 + 1024 + h*64]
    const long kqrow = (long)(b * 2048) * 3072 + 1024 + h * 64;
    const long vbase = (long)bh * 64 * 2048;

#define LOADT(kt) \
    kpA = *(const bf16x8*)&qkv[kqrow + (long)((kt) + sr) * 3072 + sc];      \
    kpB = *(const bf16x8*)&qkv[kqrow + (long)((kt) + sr) * 3072 + sc + 8];  \
    vpA = *(const bf16x8*)&vT[vbase + (long)sr * 2048 + (kt) + sc];         \
    vpB = *(const bf16x8*)&vT[vbase + (long)sr * 2048 + (kt) + sc + 8];

#define STORET(buf) \
    *(bf16x8*)&Ks[buf][sr * 72 + sc]     = kpA;  \
    *(bf16x8*)&Ks[buf][sr * 72 + sc + 8] = kpB;  \
    *(bf16x8*)&Vs[buf][sr * 72 + sc]     = vpA;  \
    *(bf16x8*)&Vs[buf][sr * 72 + sc + 8] = vpB;

// QK^T + exp2 + pack for one q-group (AQ) into two packed A-frags (AP0,AP1)
#define SCORE(AQ, AP0, AP1, KF0, KF1, KF2, KF3, SUB) \
    {                                                                                      \
        f32x16 s = {};                                                                     \
        s = __builtin_amdgcn_mfma_f32_32x32x16_bf16(KF0, AQ[0], s, 0, 0, 0);               \
        s = __builtin_amdgcn_mfma_f32_32x32x16_bf16(KF1, AQ[1], s, 0, 0, 0);               \
        s = __builtin_amdgcn_mfma_f32_32x32x16_bf16(KF2, AQ[2], s, 0, 0, 0);               \
        s = __builtin_amdgcn_mfma_f32_32x32x16_bf16(KF3, AQ[3], s, 0, 0, 0);               \
        unsigned pu[16];                                                                   \
        for (int j = 0; j < 16; ++j)                                                       \
            pu[j] = fbits(__builtin_amdgcn_exp2f(s[j] - (SUB)));                           \
        uint4 a0u, a1u;                                                                    \
        a0u.x = __builtin_amdgcn_perm(pu[1],  pu[0],  0x07060302u);                        \
        a0u.y = __builtin_amdgcn_perm(pu[3],  pu[2],  0x07060302u);                        \
        a0u.z = __builtin_amdgcn_perm(pu[5],  pu[4],  0x07060302u);                        \
        a0u.w = __builtin_amdgcn_perm(pu[7],  pu[6],  0x07060302u);                        \
        a1u.x = __builtin_amdgcn_perm(pu[9],  pu[8],  0x07060302u);                        \
        a1u.y = __builtin_amdgcn_perm(pu[11], pu[10], 0x07060302u);                        \
        a1u.z = __builtin_amdgcn_perm(pu[13], pu[12], 0x07060302u);                        \
        a1u.w = __builtin_amdgcn_perm(pu[15], pu[14], 0x07060302u);                        \
        __builtin_memcpy(&AP0, &a0u, 16); __builtin_memcpy(&AP1, &a1u, 16);                \
    }

#define ATTN_STEP(KS, VS, SUB) \
    for (int ktile = 0; ktile < 2; ++ktile) {                                              \
        const unsigned short* krow = &KS[(ktile * 32 + prow) * 72 + half * 8];             \
        bf16x8 kf0 = *(const bf16x8*)&krow[0];                                             \
        bf16x8 kf1 = *(const bf16x8*)&krow[16];                                            \
        bf16x8 kf2 = *(const bf16x8*)&krow[32];                                            \
        bf16x8 kf3 = *(const bf16x8*)&krow[48];                                            \
        bf16x8 apA0, apA1, apB0, apB1;                                                     \
        SCORE(aqA, apA0, apA1, kf0, kf1, kf2, kf3, SUB)                                    \
        SCORE(aqB, apB0, apB1, kf0, kf1, kf2, kf3, SUB)                                    \
        for (int c = 0; c < 2; ++c) {                                                      \
            bf16x8 aA = c ? apA1 : apA0;                                                   \
            bf16x8 aB = c ? apB1 : apB0;                                                   \
            bf16x8 bv0 = *(const bf16x8*)&VS[m32 * 72        + ktile * 32 + c * 16 + half * 8]; \
            bf16x8 bv1 = *(const bf16x8*)&VS[(32 + m32) * 72 + ktile * 32 + c * 16 + half * 8]; \
            oA0 = __builtin_amdgcn_mfma_f32_32x32x16_bf16(aA, bv0, oA0, 0, 0, 0);          \
            oA1 = __builtin_amdgcn_mfma_f32_32x32x16_bf16(aA, bv1, oA1, 0, 0, 0);          \
            lA  = __builtin_amdgcn_mfma_f32_32x32x16_bf16(aA, ones, lA, 0, 0, 0);          \
            oB0 = __builtin_amdgcn_mfma_f32_32x32x16_bf16(aB, bv0, oB0, 0, 0, 0);          \
            oB1 = __builtin_amdgcn_mfma_f32_32x32x16_bf16(aB, bv1, oB1, 0, 0, 0);          \
            lB  = __builtin_amdgcn_mfma_f32_32x32x16_bf16(aB, ones, lB, 0, 0, 0);          \
        }                                                                                  \
    }

#define KLOOP(SUB) \
    for (int kt = 0; kt < 2048; kt += 128) {                 \
        LOADT(kt + 64)                                       \
        ATTN_STEP(Ks[0], Vs[0], SUB)                         \
        STORET(1)                                            \
        __syncthreads();                                     \
        const bool more = (kt + 128) < 2048;                 \
        if (more) { LOADT(kt + 128) }                        \
        ATTN_STEP(Ks[1], Vs[1], SUB)                         \
        if (more) {                                          \
            STORET(0)                                        \
            __syncthreads();                                 \
        }                                                    \
    }

    bf16x8 kpA, kpB, vpA, vpB;
    LOADT(0)
    STORET(0)
    __syncthreads();

    if (c2 < 30.0f) {      // wave-uniform; scale=4 here => fast path
        KLOOP(0.0f)        // s - 0.0f folds away: no per-score VALU shift
    } else {
        KLOOP(c2)          // overflow-safe general path
    }
#undef LOADT
#undef STORET
#undef SCORE
#undef ATTN_STEP
#undef KLOOP

    // epilogue: divide by rowsum (lacc reg r matches o reg r), write attn[B,L,C]
    for (int r = 0; r < 16; ++r) {
        int m = (r & 3) + 8 * (r >> 2) + 4 * half;
        float invA = 1.0f / lA[r];
        long dstA = (long)(b * 2048 + q0 + m) * 1024 + h * 64;
        attn[dstA + m32]      = f2bf(oA0[r] * invA);
        attn[dstA + 32 + m32] = f2bf(oA1[r] * invA);
        float invB = 1.0f / lB[r];
        long dstB = (long)(b * 2048 + q0 + 32 + m) * 1024 + h * 64;
        attn[dstB + m32]      = f2bf(oB0[r] * invB);
        attn[dstB + 32 + m32] = f2bf(oB1[r] * invB);
    }
}

// ---------------------------------------------------------------------------
extern "C" void kernel_launch(void* const* d_in, const int* in_sizes, int n_in,
                              void* d_out, int out_size, void* d_ws, size_t ws_size,
                              hipStream_t stream) {
    const float* x    = (const float*)d_in[0];
    const float* Wqkv = (const float*)d_in[1];
    const float* qbia = (const float*)d_in[2];
    const float* vbia = (const float*)d_in[3];
    const float* sml  = (const float*)d_in[4];
    const float* Wp   = (const float*)d_in[5];
    const float* bp   = (const float*)d_in[6];

    char* ws = (char*)d_ws;
    unsigned short* qkv   = (unsigned short*)ws;                    // [0, 50.33MB)
    unsigned short* Wqkvb = (unsigned short*)(ws + 50331648);       // 6.29MB
    unsigned short* vT    = (unsigned short*)(ws + 67108864);       // hosts xb first
    unsigned short* xb    = vT;
    unsigned short* attnb = (unsigned short*)(ws + 83886080);
    float*          bias3 = (float*)(ws + 100663296);               // 12KB
    unsigned short* Wpb   = (unsigned short*)(ws + 100679680);      // 2MB
    float*          out   = (float*)d_out;

    hipLaunchKernelGGL(k_prep, dim3(6146), dim3(256), 0, stream,
                       x, Wqkv, Wp, qbia, vbia, xb, Wqkvb, Wpb, bias3);
    hipLaunchKernelGGL((k_gemm_lds<false, true>), dim3(64, 24), dim3(256), 0, stream,
                       xb, Wqkvb, bias3, (void*)qkv, 3072, 1024);
    hipLaunchKernelGGL(k_prep_v, dim3(32, 64), dim3(256), 0, stream, qkv, vT);
    hipLaunchKernelGGL(k_attn32, dim3(512), dim3(256), 0, stream, qkv, vT, sml, attnb);
    hipLaunchKernelGGL((k_gemm_lds<true, false>), dim3(64, 8), dim3(256), 0, stream,
                       attnb, Wpb, bp, (void*)out, 1024, 1024);
}